// Round 5
// baseline (309.525 us; speedup 1.0000x reference)
//
#include <hip/hip_runtime.h>
#include <hip/hip_bf16.h>

// Problem constants (match reference)
constexpr int NE  = 8;     // experts
constexpr int T   = 2048;  // tokens
constexpr int IN  = 2048;  // reduction dim
constexpr int OUT = 2048;  // output dim
constexpr int GS  = 64;    // quant group size
constexpr int G   = IN / GS;

// Weight-stationary tiling: block owns (e, n-tile of 64, k-chunk of 512).
// B dequanted ONCE into LDS; token loop barrier-free; epilogue = plain
// stores to per-kchunk partial slabs (no atomics) + reduce kernel.
constexpr int BN = 64;
constexpr int KC = 512;
constexpr int KSPLIT = IN / KC;    // 4
constexpr int LDB = KC + 8;

using short8  = __attribute__((ext_vector_type(8))) short;
using floatx4 = __attribute__((ext_vector_type(4))) float;

// x fp32 -> bf16 pre-pass
__global__ __launch_bounds__(256)
void cvt_x_bf16(const float* __restrict__ x, __hip_bfloat16* __restrict__ xb) {
    const int i = (blockIdx.x * 256 + threadIdx.x) * 4;
    const float4 v = *(const float4*)(x + i);
    union { unsigned long long u; __hip_bfloat162 h2[2]; } p;
    p.h2[0] = __float22bfloat162_rn(float2{v.x, v.y});
    p.h2[1] = __float22bfloat162_rn(float2{v.z, v.w});
    *(unsigned long long*)(xb + i) = p.u;
}

// sum 4 partial slabs -> out (partials likely L3-resident)
__global__ __launch_bounds__(256)
void reduce_part(const float* __restrict__ part, float* __restrict__ out) {
    const size_t i = ((size_t)blockIdx.x * 256 + threadIdx.x) * 4;
    float4 s = *(const float4*)(part + i);
#pragma unroll
    for (int p = 1; p < KSPLIT; ++p) {
        const float4 v = *(const float4*)(part + (size_t)p * T * OUT + i);
        s.x += v.x; s.y += v.y; s.z += v.z; s.w += v.w;
    }
    *(float4*)(out + i) = s;
}

template <bool ATOMIC>
__global__ __launch_bounds__(256, 2)
void hqq_grouped_gemm(const __hip_bfloat16* __restrict__ xb,
                      const int*   __restrict__ qw,
                      const float* __restrict__ snz,   // [E][G][OUT][2]
                      const int*   __restrict__ tpe,   // [E]
                      float* __restrict__ outp) {      // ATOMIC: out; else partial base
    const int tid = threadIdx.x;
    const int e   = blockIdx.z;
    const int kci = blockIdx.y;
    const int kc  = kci * KC;
    const int n0  = blockIdx.x * BN;

    int b0 = 0;
    for (int i = 0; i < NE; ++i) {
        int c = tpe[i];
        if (i < e) b0 += c;
    }
    const int b1 = b0 + tpe[e];
    const int nrows = b1 - b0;
    if (nrows <= 0) return;

    __shared__ __hip_bfloat16 Bs[BN][LDB];  // TRANSPOSED [n][k], bf16

    // ---- stage + dequant B-slab ONCE: 512k x 64n codes ----
    const int bn_ = tid & 63;
    const int ko  = (tid >> 6) * 8;
    const int*    qcol  = qw + (size_t)e * IN * OUT + (size_t)kc * OUT + n0 + bn_;
    const float2* szcol = (const float2*)snz + (size_t)e * G * OUT + n0 + bn_;

#pragma unroll 8
    for (int i = 0; i < 16; ++i) {
        const int kb = ko + 32 * i;
        const int g  = (kc + kb) >> 6;
        const float2 sz = szcol[(size_t)g * OUT];
        const float s = sz.x;
        const float c = sz.y - 8.0f * s;          // (q-8)*s+z == q*s+c
        const int* qp = qcol + (size_t)kb * OUT;
        int q[8];
#pragma unroll
        for (int j = 0; j < 8; ++j)
            q[j] = qp[(size_t)j * OUT];
        union { short8 v; __hip_bfloat162 h2[4]; } pb;
#pragma unroll
        for (int j = 0; j < 4; ++j) {
            const float f0 = (float)q[2 * j]     * s + c;
            const float f1 = (float)q[2 * j + 1] * s + c;
            pb.h2[j] = __float22bfloat162_rn(float2{f0, f1});
        }
        *(short8*)&Bs[bn_][kb] = pb.v;
    }

    __syncthreads();   // the ONLY barrier

    // ---- token loop: 32-row wave-tiles, wave-strided, barrier-free ----
    const int lane = tid & 63;
    const int wid  = tid >> 6;
    const int lm = lane & 15;
    const int lk = (lane >> 4) * 8;
    const int lq = (lane >> 4) * 4;

    float* const obase = ATOMIC ? outp : outp + (size_t)kci * T * OUT;

    for (int mt = wid; mt * 32 < nrows; mt += 4) {
        const int r0 = b0 + mt * 32;

        const __hip_bfloat16* abase[2];
#pragma unroll
        for (int i = 0; i < 2; ++i) {
            const int row = r0 + i * 16 + lm;
            const int rr  = row < b1 ? row : (b1 - 1);   // clamp; never stored
            abase[i] = xb + (size_t)rr * IN + kc + lk;
        }

        floatx4 acc[2][4];
#pragma unroll
        for (int i = 0; i < 2; ++i)
#pragma unroll
            for (int j = 0; j < 4; ++j)
                acc[i][j] = (floatx4){0.f, 0.f, 0.f, 0.f};

        // software pipeline: chunks of 4 k-steps (128 k), depth-2 A prefetch
        short8 bufA[8], bufB[8];   // [step*2 + i], 32 VGPR each
        auto loadc = [&](short8* buf, int c) {
            const int ksb = c * 128;
#pragma unroll
            for (int s = 0; s < 4; ++s)
#pragma unroll
                for (int i = 0; i < 2; ++i)
                    buf[s * 2 + i] = *(const short8*)(abase[i] + ksb + s * 32);
        };
        auto mfmac = [&](short8* buf, int c) {
            const int ksb = c * 128;
#pragma unroll
            for (int s = 0; s < 4; ++s) {
                short8 bfr[4];
#pragma unroll
                for (int j = 0; j < 4; ++j)
                    bfr[j] = *(const short8*)&Bs[j * 16 + lm][ksb + s * 32 + lk];
#pragma unroll
                for (int i = 0; i < 2; ++i)
#pragma unroll
                    for (int j = 0; j < 4; ++j)
                        acc[i][j] = __builtin_amdgcn_mfma_f32_16x16x32_bf16(
                            buf[s * 2 + i], bfr[j], acc[i][j], 0, 0, 0);
            }
        };
        loadc(bufA, 0); loadc(bufB, 1);     // depth-2 in flight
        mfmac(bufA, 0); loadc(bufA, 2);
        mfmac(bufB, 1); loadc(bufB, 3);
        mfmac(bufA, 2);
        mfmac(bufB, 3);

        // epilogue: C/D layout col=lane&15, row=(lane>>4)*4+reg
#pragma unroll
        for (int i = 0; i < 2; ++i) {
#pragma unroll
            for (int r = 0; r < 4; ++r) {
                const int row = r0 + i * 16 + lq + r;
                if (row < b1) {
                    float* op = obase + (size_t)row * OUT + n0 + lm;
#pragma unroll
                    for (int j = 0; j < 4; ++j) {
                        if (ATOMIC) atomicAdd(op + j * 16, acc[i][j][r]);
                        else        op[j * 16] = acc[i][j][r];
                    }
                }
            }
        }
    }
}

extern "C" void kernel_launch(void* const* d_in, const int* in_sizes, int n_in,
                              void* d_out, int out_size, void* d_ws, size_t ws_size,
                              hipStream_t stream) {
    const float* x   = (const float*)d_in[0];
    const int*   qw  = (const int*)d_in[1];
    const float* snz = (const float*)d_in[2];
    const int*   tpe = (const int*)d_in[3];
    float* out = (float*)d_out;

    const size_t xb_bytes   = (size_t)T * IN * sizeof(__hip_bfloat16);   // 8.4 MB
    const size_t part_bytes = (size_t)KSPLIT * T * OUT * sizeof(float);  // 67.1 MB

    __hip_bfloat16* xb = (__hip_bfloat16*)d_ws;
    cvt_x_bf16<<<(T * IN) / (256 * 4), 256, 0, stream>>>(x, xb);

    dim3 grid(OUT / BN, KSPLIT, NE);   // 32 x 4 x 8 = 1024 blocks, all working

    if (ws_size >= xb_bytes + part_bytes) {
        // no-atomic path: plain stores to partial slabs + reduce
        float* part = (float*)((char*)d_ws + xb_bytes);
        hqq_grouped_gemm<false><<<grid, 256, 0, stream>>>(xb, qw, snz, tpe, part);
        reduce_part<<<(T * OUT) / (256 * 4), 256, 0, stream>>>(part, out);
    } else {
        // fallback: atomic accumulation into zeroed out
        hipMemsetAsync(out, 0, (size_t)out_size * sizeof(float), stream);
        hqq_grouped_gemm<true><<<grid, 256, 0, stream>>>(xb, qw, snz, tpe, out);
    }
}